// Round 1
// baseline (258.581 us; speedup 1.0000x reference)
//
#include <hip/hip_runtime.h>
#include <stdint.h>

#define N_TOKENS 32768
#define N_CODES  8192
#define DIM      256
#define EPSF     1e-8f

typedef __bf16 bf16x8 __attribute__((ext_vector_type(8)));
typedef float  f32x4  __attribute__((ext_vector_type(4)));

// ws layout: [bf16 codebooks 4MiB][cnorm f32 32KiB][hist i32 32KiB]
#define WS_CNORM_OFF  (4u*1024u*1024u)
#define WS_HIST_OFF   (WS_CNORM_OFF + N_CODES*4u)

// ---------------------------------------------------------------------------
// K1: codebooks fp32 -> bf16, ||c||^2, zero histogram.
// ---------------------------------------------------------------------------
__global__ __launch_bounds__(256) void k_prep(const float* __restrict__ cbf,
                                              unsigned short* __restrict__ cbh,
                                              float* __restrict__ cnorm,
                                              int* __restrict__ hist) {
    const int tid = blockIdx.x * 256 + threadIdx.x;
    if (tid < N_CODES) hist[tid] = 0;

    const int w = threadIdx.x >> 6;
    const int lane = threadIdx.x & 63;
    const int row = blockIdx.x * 4 + w;

    const float4 v = ((const float4*)(cbf + (size_t)row * DIM))[lane];
    float sq = v.x * v.x + v.y * v.y + v.z * v.z + v.w * v.w;

    ushort4 u;
    u.x = __builtin_bit_cast(unsigned short, (__bf16)v.x);
    u.y = __builtin_bit_cast(unsigned short, (__bf16)v.y);
    u.z = __builtin_bit_cast(unsigned short, (__bf16)v.z);
    u.w = __builtin_bit_cast(unsigned short, (__bf16)v.w);
    ((ushort4*)(cbh + (size_t)row * DIM))[lane] = u;

    #pragma unroll
    for (int d = 1; d < 64; d <<= 1) sq += __shfl_xor(sq, d);
    if (lane == 0) cnorm[row] = sq;
}

// ---------------------------------------------------------------------------
// K2: fused distance-matmul + argmax(x.c - cn/2) + quant epilogue, v6.
//  v6 change vs v5b: kill the per-chunk full-drain lockstep.
//  - THREE rotating 32KB staging buffers (prefetch distance 2 chunks).
//  - Raw `s_waitcnt vmcnt(N); s_barrier` per chunk with COUNTED N (4, or 5
//    for wave 0 which also DMAs cnorm; 0 only on the last iteration).
//    Each wave waits only its OWN stage(cc) group (issued 2 chunks ago ->
//    ~free); the barrier makes it collective. stage(cc+1)/stage(cc+2) stay
//    in flight ACROSS the barrier (T4) instead of draining every chunk.
//  - Buffer-overwrite safety: stage(cc+2) targets buf[(cc+2)%3], last read
//    at iteration cc-1; it is issued AFTER iteration cc's barrier, which
//    orders all waves' cc-1 reads before the new DMA writes.
//  - s_setprio(1) around the MFMA cluster (T5).
//  - NO other vmem ops may exist in the main loop (vmcnt counting!).
// ---------------------------------------------------------------------------
__global__ __launch_bounds__(512, 2) void k_argmin(const float* __restrict__ X,
                                                   const float* __restrict__ R,
                                                   const unsigned short* __restrict__ cbh,
                                                   const float* __restrict__ cnorm,
                                                   float* __restrict__ out,
                                                   int* __restrict__ hist) {
    // layout: [0,32768) buf0 | [32768,65536) buf1 | [65536,98304) buf2
    //         [98304,99072) cnS[3][64] | [99072,101120) redv[8][64]
    //         [101120,103168) redi[8][64] | [103168,103680) maxvS[128]
    // A-stage (128 tok x 544B = 69632B) transiently overlays [0,69632).
    __shared__ __attribute__((aligned(16))) char smem[103680];
    float* cnS   = (float*)(smem + 98304);
    float* redv  = (float*)(smem + 99072);
    int*   redi  = (int*)(smem + 101120);
    float* maxvS = (float*)(smem + 103168);

    const int tid  = threadIdx.x;
    const int w    = tid >> 6;
    const int lane = tid & 63;
    const int lr   = lane & 15;
    const int lq   = lane >> 4;
    const int th   = w >> 2;          // token half
    const int wc   = w & 3;           // code quarter
    const int r0   = blockIdx.x * 128;
    const int mycol = wc * 16 + lr;

    // ---- A-stage: wave w loads tokens [16w,16w+16), row stride 544B ----
    {
        const float4* Xf4 = (const float4*)(X + (size_t)(r0 + 16 * w) * DIM);
        #pragma unroll
        for (int i = 0; i < 16; ++i) {
            const float4 v = Xf4[i * 64 + lane];
            ushort4 u;
            u.x = __builtin_bit_cast(unsigned short, (__bf16)v.x);
            u.y = __builtin_bit_cast(unsigned short, (__bf16)v.y);
            u.z = __builtin_bit_cast(unsigned short, (__bf16)v.z);
            u.w = __builtin_bit_cast(unsigned short, (__bf16)v.w);
            *(ushort4*)(smem + (16 * w + i) * 544 + lane * 8) = u;
        }
    }
    __syncthreads();

    bf16x8 A[4][8];
    #pragma unroll
    for (int mf = 0; mf < 4; ++mf)
        #pragma unroll
        for (int kc = 0; kc < 8; ++kc)
            A[mf][kc] = *(const bf16x8*)(smem + (64 * th + mf * 16 + lr) * 544 + kc * 64 + lq * 16);
    __syncthreads();   // A reads done before chunk-0 staging overwrites smem

    // ---- staging source offsets: wave w stages codes [8w, 8w+8), 4 DMAs ----
    const int half = lane >> 5, l5 = lane & 31;
    int srcoff[4];
    #pragma unroll
    for (int s = 0; s < 4; ++s) {
        const int c = 8 * w + 2 * s + half;   // code row this lane helps stage
        const int j = (l5 - c) & 31;          // source 16B-chunk landing in slot l5
        srcoff[s] = c * 512 + j * 16;
    }
    const char* cbb = (const char*)cbh;

    // ---- prologue: stage chunks 0 and 1 (groups of 4 DMAs; +1 cn on w0) ----
    #pragma unroll
    for (int p = 0; p < 2; ++p) {
        const char* src = cbb + (size_t)p * 32768;
        #pragma unroll
        for (int s = 0; s < 4; ++s)
            __builtin_amdgcn_global_load_lds(
                (const __attribute__((address_space(1))) unsigned int*)(src + srcoff[s]),
                (__attribute__((address_space(3))) unsigned int*)(smem + p * 32768 + w * 4096 + s * 1024),
                16, 0, 0);
        if (w == 0)
            __builtin_amdgcn_global_load_lds(
                (const __attribute__((address_space(1))) unsigned int*)(cnorm + p * 64 + lane),
                (__attribute__((address_space(3))) unsigned int*)(cnS + p * 64),
                4, 0, 0);
    }

    float maxv[16];
    int   maxi[16];
    #pragma unroll
    for (int i = 0; i < 16; ++i) { maxv[i] = -3.4e38f; maxi[i] = 0; }

    int cur = 0;   // byte offset of chunk cc's buffer: (cc % 3) * 32768
    for (int cc = 0; cc < 128; ++cc) {
        // counted wait on OWN stage(cc) group, then collective barrier.
        // steady state: outstanding <= stage(cc) + stage(cc+1) = 2 groups;
        // vmcnt(groupsize) retires the older group. Never drains the queue.
        if (cc == 127) {
            asm volatile("s_waitcnt vmcnt(0)\n\ts_barrier" ::: "memory");
        } else if (w == 0) {
            asm volatile("s_waitcnt vmcnt(5)\n\ts_barrier" ::: "memory");
        } else {
            asm volatile("s_waitcnt vmcnt(4)\n\ts_barrier" ::: "memory");
        }

        // issue stage(cc+2) into buf[(cc+2)%3] (safe: last read at cc-1,
        // ordered before this point by the barrier above).
        if (cc + 2 < 128) {
            int stg = cur + 65536; if (stg >= 98304) stg -= 98304;
            const char* src = cbb + (size_t)(cc + 2) * 32768;
            #pragma unroll
            for (int s = 0; s < 4; ++s)
                __builtin_amdgcn_global_load_lds(
                    (const __attribute__((address_space(1))) unsigned int*)(src + srcoff[s]),
                    (__attribute__((address_space(3))) unsigned int*)(smem + stg + w * 4096 + s * 1024),
                    16, 0, 0);
            if (w == 0)
                __builtin_amdgcn_global_load_lds(
                    (const __attribute__((address_space(1))) unsigned int*)(cnorm + (cc + 2) * 64 + lane),
                    (__attribute__((address_space(3))) unsigned int*)(cnS + (stg >> 9)),
                    4, 0, 0);
        }

        const float cinit = -0.5f * cnS[(cur >> 9) + mycol];
        f32x4 acc[4];
        #pragma unroll
        for (int mf = 0; mf < 4; ++mf) {
            acc[mf][0] = cinit; acc[mf][1] = cinit; acc[mf][2] = cinit; acc[mf][3] = cinit;
        }

        __builtin_amdgcn_s_setprio(1);
        #pragma unroll
        for (int kc = 0; kc < 8; ++kc) {
            const bf16x8 b = *(const bf16x8*)(smem + cur + mycol * 512 +
                                              (((kc * 4 + lq + mycol) & 31) << 4));
            #pragma unroll
            for (int mf = 0; mf < 4; ++mf)
                acc[mf] = __builtin_amdgcn_mfma_f32_16x16x32_bf16(A[mf][kc], b, acc[mf], 0, 0, 0);
        }
        __builtin_amdgcn_s_setprio(0);

        const int col = cc * 64 + mycol;
        #pragma unroll
        for (int mf = 0; mf < 4; ++mf)
            #pragma unroll
            for (int r = 0; r < 4; ++r) {
                const float v = acc[mf][r];
                const int j = mf * 4 + r;
                if (v > maxv[j]) { maxv[j] = v; maxi[j] = col; }
            }

        cur += 32768; if (cur >= 98304) cur -= 98304;
    }

    // ---- reduce across the 16 lanes (lr) sharing each token row ----
    #pragma unroll
    for (int mf = 0; mf < 4; ++mf)
        #pragma unroll
        for (int r = 0; r < 4; ++r) {
            float v = maxv[mf * 4 + r]; int ix = maxi[mf * 4 + r];
            #pragma unroll
            for (int d = 1; d <= 8; d <<= 1) {
                const float ov = __shfl_xor(v, d);
                const int   oi = __shfl_xor(ix, d);
                if (ov > v || (ov == v && oi < ix)) { v = ov; ix = oi; }
            }
            if (lr == 0) {
                const int row = mf * 16 + lq * 4 + r;   // token row within half
                redv[w * 64 + row] = v; redi[w * 64 + row] = ix;
            }
        }
    __syncthreads();

    // ---- combine the 4 code-quarter waves per token; hist + maxvS ----
    if (tid < 128) {
        const int t = tid, tth = t >> 6, tl = t & 63;
        float v = redv[(4 * tth) * 64 + tl]; int ix = redi[(4 * tth) * 64 + tl];
        #pragma unroll
        for (int ww = 1; ww < 4; ++ww) {
            const float ov = redv[(4 * tth + ww) * 64 + tl];
            const int   oi = redi[(4 * tth + ww) * 64 + tl];
            if (ov > v || (ov == v && oi < ix)) { v = ov; ix = oi; }
        }
        maxvS[t] = v;
        atomicAdd(&hist[ix], 1);
    }
    __syncthreads();

    // ---- fused quant epilogue: wave w handles tokens [16w, 16w+16) ----
    for (int i = 0; i < 16; ++i) {
        const int tl = 16 * w + i;
        const int tok = r0 + tl;
        const float4 x = ((const float4*)(X + (size_t)tok * DIM))[lane];
        const float4 r = ((const float4*)(R + (size_t)tok * DIM))[lane];

        float x2 = x.x * x.x + x.y * x.y + x.z * x.z + x.w * x.w;
        float n2 = r.x * r.x + r.y * r.y + r.z * r.z + r.w * r.w;
        #pragma unroll
        for (int d = 1; d < 64; d <<= 1) {
            x2 += __shfl_xor(x2, d);
            n2 += __shfl_xor(n2, d);
        }
        const float mv = maxvS[tl];
        const float d2 = fmaxf(fmaf(-2.f, mv, x2), 0.f);
        const float s = sqrtf(d2) / (sqrtf(n2) + EPSF);

        float4 o;
        o.x = fmaf(s, r.x, x.x);
        o.y = fmaf(s, r.y, x.y);
        o.z = fmaf(s, r.z, x.z);
        o.w = fmaf(s, r.w, x.w);
        ((float4*)(out + (size_t)tok * DIM))[lane] = o;
    }
}

// ---------------------------------------------------------------------------
// K3: perplexity + num_unique from histogram. single block, 1024 thr.
// ---------------------------------------------------------------------------
__global__ __launch_bounds__(1024) void k_stats(const int* __restrict__ hist,
                                                float* __restrict__ outs) {
    float s = 0.f; int u = 0;
    for (int b = threadIdx.x; b < N_CODES; b += 1024) {
        const float c = (float)hist[b];
        if (c > 0.f) ++u;
        const float p = c * (1.f / (float)N_TOKENS);
        s += p * logf(p + EPSF);
    }
    #pragma unroll
    for (int d = 1; d < 64; d <<= 1) {
        s += __shfl_xor(s, d);
        u += __shfl_xor(u, d);
    }
    __shared__ float ss[16];
    __shared__ int   su[16];
    const int w = threadIdx.x >> 6, lane = threadIdx.x & 63;
    if (lane == 0) { ss[w] = s; su[w] = u; }
    __syncthreads();
    if (threadIdx.x == 0) {
        float st = 0.f; int ut = 0;
        #pragma unroll
        for (int i = 0; i < 16; ++i) { st += ss[i]; ut += su[i]; }
        outs[0] = expf(-st);       // perplexity
        outs[1] = (float)ut;       // num_unique_indices
    }
}

// ---------------------------------------------------------------------------
extern "C" void kernel_launch(void* const* d_in, const int* in_sizes, int n_in,
                              void* d_out, int out_size, void* d_ws, size_t ws_size,
                              hipStream_t stream) {
    const float* X = (const float*)d_in[0];  // input_data (32768,256)
    const float* R = (const float*)d_in[1];  // rand       (32768,256)
    const float* C = (const float*)d_in[2];  // codebooks  (8192,256)
    float* out = (float*)d_out;

    char* ws = (char*)d_ws;
    unsigned short* cbh = (unsigned short*)ws;             // bf16 codebooks
    float* cnorm = (float*)(ws + WS_CNORM_OFF);
    int*   hist  = (int*)(ws + WS_HIST_OFF);

    k_prep  <<<N_CODES / 4,    256, 0, stream>>>(C, cbh, cnorm, hist);
    k_argmin<<<N_TOKENS / 128, 512, 0, stream>>>(X, R, cbh, cnorm, out, hist);
    k_stats <<<1, 1024, 0, stream>>>(hist, out + (size_t)N_TOKENS * DIM);
}